// Round 8
// baseline (412.761 us; speedup 1.0000x reference)
//
#include <hip/hip_runtime.h>
#include <float.h>

// EdgeConv: B=4, N=4096, Fin=64, Fout=64, K=20
// out[b,n,o] = u[b,n,o] + max_{m in knn20(n)} v[b,m,o]
//   u = x.(W1-W2)^T + bias ; v = x.W2^T
// knn on d = sq[n] + sq[m] - 2 x_n.x_m (>=0), self excluded.
//
// R8: FUSED knn. R5-R7 evidence: the global key-buffer round trip
// (~170-320 MB write + ~90 MB read) is the structural bottleneck. Fix:
// one block computes 16 n-rows x all 4096 m with mfma_16x16x32_bf16
// (hi-bf16 only; error << key quantum, covered by +4 quantum margin and
// exact fp32 recompute), compresses keys 4:1 via quad-min into 33 KB LDS,
// then per-wave register bisection + collect + exact recompute + top-20
// extraction + v-gather, all in the same kernel. Keys never leave the CU.

constexpr int Bb = 4, Nn = 4096, Ff = 64, Kk = 20;
constexpr int NB = 16;         // n-rows per fused block
constexpr int QSTRIDE = 1032;  // u16 per LDS quad row (1024 + 8 pad)
constexpr int CCAP = 64;       // candidate quads per row

typedef __attribute__((ext_vector_type(8))) short bf16x8;
typedef __attribute__((ext_vector_type(4))) float f32x4;

__device__ inline unsigned int bf16rn(float f) {
  unsigned int u = __float_as_uint(f);
  return (u + 0x7fffu + ((u >> 16) & 1u)) >> 16;
}

// ---------------- K1: u, v, sq, xhi (16-row fragment swizzle) ----------------
constexpr int RT1 = 16;  // rows per block

__global__ __launch_bounds__(256) void uv_kernel2(
    const float* __restrict__ x, const float* __restrict__ W,
    const float* __restrict__ bvec, float* __restrict__ u,
    float* __restrict__ v, float* __restrict__ sq,
    unsigned short* __restrict__ xhi) {
  __shared__ __align__(16) float4 Ws[64 * 33];   // W row o at granules [33o,33o+32)
  __shared__ __align__(16) float4 xs[RT1 * 16];  // x row r at [16r..)
  const int t = threadIdx.x, l = t & 63, w = t >> 6;
  const int bn0 = blockIdx.x * RT1;
  #pragma unroll
  for (int i = 0; i < 8; i++) {
    int f = t + 256 * i;  // f4 index into W (64 rows x 32 f4)
    Ws[(f >> 5) * 33 + (f & 31)] = ((const float4*)W)[f];
  }
  xs[t] = ((const float4*)x)[bn0 * 16 + t];
  __syncthreads();
  // bf16 split -> 16-row MFMA-fragment swizzle:
  // flat = (ng>>4)*1024 + (k>>5)*512 + ((k>>3)&3)*128 + (ng&15)*8 + (k&7)
  #pragma unroll
  for (int i = 0; i < 4; i++) {
    int idx = t + 256 * i;   // 0..1023 within block's 16 rows
    int nloc = idx >> 6;     // row within block
    int k = idx & 63;        // channel
    float val = ((const float*)xs)[idx];
    unsigned int hb = bf16rn(val);
    int ng = bn0 + nloc;  // global flat row
    size_t flat = ((size_t)(ng >> 4) << 10) + ((size_t)(k >> 5) << 9) +
                  ((size_t)((k >> 3) & 3) << 7) + ((size_t)(ng & 15) << 3) +
                  (size_t)(k & 7);
    xhi[flat] = (unsigned short)hb;
  }
  // sq for rows 4w..4w+3
  #pragma unroll
  for (int i = 0; i < 4; i++) {
    int r = 4 * w + i;
    float val = ((const float*)&xs[r * 16])[l];
    float s = val * val;
    #pragma unroll
    for (int d = 32; d; d >>= 1) s += __shfl_xor(s, d, 64);
    if (l == 0) sq[bn0 + r] = s;
  }
  const int o = l;
  float ua[4] = {0.f, 0.f, 0.f, 0.f}, va[4] = {0.f, 0.f, 0.f, 0.f};
  #pragma unroll
  for (int c = 0; c < 16; c++) {
    float4 w1 = Ws[o * 33 + c];
    float4 w2 = Ws[o * 33 + 16 + c];
    float4 wd;
    wd.x = w1.x - w2.x; wd.y = w1.y - w2.y;
    wd.z = w1.z - w2.z; wd.w = w1.w - w2.w;
    #pragma unroll
    for (int i = 0; i < 4; i++) {
      float4 xv = xs[(4 * w + i) * 16 + c];
      ua[i] += xv.x * wd.x + xv.y * wd.y + xv.z * wd.z + xv.w * wd.w;
      va[i] += xv.x * w2.x + xv.y * w2.y + xv.z * w2.z + xv.w * w2.w;
    }
  }
  float bo = bvec[o];
  #pragma unroll
  for (int i = 0; i < 4; i++) {
    size_t row = (size_t)(bn0 + 4 * w + i);
    u[row * 64 + o] = ua[i] + bo;
    v[row * 64 + o] = va[i];
  }
}

// ---------------- Fused knn: keys + quad-min + select + output ------------
// Grid 1024 blocks (4 batches x 256 n-tiles of 16 rows). Block = 4 waves.
// Wave w computes m in [w*1024, (w+1)*1024) for all 16 rows.
// A/B frag (16x16x32_bf16): lane = (row|col) + 16*kquad, 8 contiguous k.
// C/D: col=lane&15, row=(lane>>4)*4+reg [m89/m91].
// Quad q (0..1023 per row): members m = (q>>4)*64 + (q&15) + 16*i, i=0..3.

__global__ __launch_bounds__(256, 4) void fused_knn_kernel(
    const float* __restrict__ x, const unsigned short* __restrict__ xhi,
    const float* __restrict__ sq, const float* __restrict__ u,
    const float* __restrict__ v, float* __restrict__ out) {
  __shared__ unsigned short qminS[NB * QSTRIDE];  // 33 KB
  __shared__ int candS[NB * CCAP];                // 4 KB
  __shared__ int ccntS[NB];

  const int t = threadIdx.x, l = t & 63, w = t >> 6;
  const int blk = blockIdx.x;
  const int b = blk >> 8;
  const int n0 = (blk & 255) * NB;  // batch-local base row
  const int gbase = b * Nn + n0;    // global flat base row
  const int c16 = l & 15;           // col / row-within-16 lane field
  const int q16 = l >> 4;           // k-quad lane field

  if (t < NB) ccntS[t] = 0;

  // A fragments: rows gbase..gbase+15, k-halves 0/1
  const size_t Abase = (size_t)(gbase >> 4) << 10;
  const bf16x8 A0 = *(const bf16x8*)(xhi + Abase + ((size_t)l << 3));
  const bf16x8 A1 = *(const bf16x8*)(xhi + Abase + 512 + ((size_t)l << 3));

  float sqn[4];
  #pragma unroll
  for (int e = 0; e < 4; e++) sqn[e] = sq[gbase + q16 * 4 + e];
  const float* sqb = sq + b * Nn;

  // ---- key phase ----
  unsigned int qmin[4];
  for (int j = 0; j < 64; ++j) {
    const int m0 = w * 1024 + 16 * j;
    const size_t Bbase = (size_t)((b * Nn + m0) >> 4) << 10;
    bf16x8 B0 = *(const bf16x8*)(xhi + Bbase + ((size_t)l << 3));
    bf16x8 B1 = *(const bf16x8*)(xhi + Bbase + 512 + ((size_t)l << 3));
    f32x4 acc = {0.f, 0.f, 0.f, 0.f};
    acc = __builtin_amdgcn_mfma_f32_16x16x32_bf16(A0, B0, acc, 0, 0, 0);
    acc = __builtin_amdgcn_mfma_f32_16x16x32_bf16(A1, B1, acc, 0, 0, 0);
    const int m = m0 + c16;
    const float sm = sqb[m];
    #pragma unroll
    for (int e = 0; e < 4; e++) {
      float d = fmaxf(sqn[e] + sm - 2.0f * acc[e], 0.f);
      unsigned int key = __float_as_uint(d) >> 15;  // monotone u16
      if (m == n0 + q16 * 4 + e) key = 0xFFFFu;     // self
      qmin[e] = ((j & 3) == 0) ? key : min(qmin[e], key);
    }
    if ((j & 3) == 3) {
      const int q = w * 256 + (j >> 2) * 16 + c16;
      #pragma unroll
      for (int e = 0; e < 4; e++)
        qminS[(q16 * 4 + e) * QSTRIDE + q] = (unsigned short)qmin[e];
    }
  }
  __syncthreads();

  // ---- selection: wave w owns rows 4w..4w+3 ----
  const float4* xb4 = (const float4*)(x + (size_t)b * Nn * Ff);
  const float* vb = v + (size_t)b * Nn * Ff;

  for (int er = 0; er < 4; ++er) {
    const int r = 4 * w + er;  // block-local row
    // load 1024 quadmins -> 8 uints (16 u16) per lane, coalesced b128
    uint4 k0 = *(const uint4*)((const char*)qminS + r * (QSTRIDE * 2) + l * 16);
    uint4 k1 = *(const uint4*)((const char*)qminS + r * (QSTRIDE * 2) + 1024 + l * 16);
    unsigned int a[8] = {k0.x, k0.y, k0.z, k0.w, k1.x, k1.y, k1.z, k1.w};

    auto countLE = [&](int mid) -> int {
      int c = 0;
      #pragma unroll
      for (int i = 0; i < 8; i++)
        c += ((int)(a[i] & 0xffffu) <= mid) + ((int)(a[i] >> 16) <= mid);
      #pragma unroll
      for (int d2 = 1; d2 < 64; d2 <<= 1) c += __shfl_xor(c, d2, 64);
      return c;
    };

    unsigned int mn = 0xffffffffu;
    #pragma unroll
    for (int i = 0; i < 8; i++)
      mn = min(mn, min(a[i] & 0xffffu, a[i] >> 16));
    #pragma unroll
    for (int d2 = 1; d2 < 64; d2 <<= 1)
      mn = min(mn, (unsigned int)__shfl_xor((int)mn, d2, 64));

    // bounded gallop + bisect on quad counts
    int lo = (int)mn - 1;
    int hi = (int)mn + 64;
    if (hi > 65530) hi = 65530;
    int c = countLE(hi);
    int step = 128;
    while (c < Kk && hi < 65530) {
      lo = hi;
      hi += step;
      if (hi > 65530) hi = 65530;
      step <<= 1;
      c = countLE(hi);
    }
    while (c > 44 && hi - lo > 1) {
      int mid = (lo + hi) >> 1;
      int cm = countLE(mid);
      if (cm >= Kk) { hi = mid; c = cm; } else { lo = mid; }
    }
    const int hc = hi + 4;  // margin: hi-only bf16 keys + quantization

    // collect qualifying quads
    #pragma unroll
    for (int i = 0; i < 8; i++) {
      int qbase = ((i & 3) * 64 + l) * 4 + (i >> 2) * 1024;  // see note below
      // uint i covers u16 indices: for i<4 (k0): (l*4 + i)*2 + h
      //                            for i>=4 (k1): 512 + (l*4 + (i-4))*2 + h
      int ubase = (i < 4) ? (l * 4 + i) * 2 : 512 + (l * 4 + (i - 4)) * 2;
      (void)qbase;
      if ((int)(a[i] & 0xffffu) <= hc) {
        int slot = atomicAdd(&ccntS[r], 1);
        if (slot < CCAP) candS[r * CCAP + slot] = ubase;
      }
      if ((int)(a[i] >> 16) <= hc) {
        int slot = atomicAdd(&ccntS[r], 1);
        if (slot < CCAP) candS[r * CCAP + slot] = ubase + 1;
      }
    }
    int C = ccntS[r];
    if (C > CCAP) C = CCAP;

    // exact fp32 distances for all 4 members of the candidate quad
    unsigned long long kc[4] = {~0ULL, ~0ULL, ~0ULL, ~0ULL};
    if (l < C) {
      int q = candS[r * CCAP + l];
      int mb = ((q >> 4) << 6) + (q & 15);
      #pragma unroll
      for (int i = 0; i < 4; i++) {
        int mI = mb + 16 * i;
        const float4* xmf = xb4 + (size_t)mI * 16;
        float ds = 0.f;
        #pragma unroll
        for (int cc = 0; cc < 16; cc++) {
          float4 an = xb4[(size_t)(n0 + r) * 16 + cc];  // wave-uniform
          float4 bm = xmf[cc];
          float dx = an.x - bm.x, dy = an.y - bm.y, dz = an.z - bm.z,
                dw2 = an.w - bm.w;
          ds += dx * dx + dy * dy + dz * dz + dw2 * dw2;
        }
        if (mI == n0 + r) ds = FLT_MAX;  // self
        kc[i] = ((unsigned long long)__float_as_uint(ds) << 32) |
                (unsigned int)mI;
      }
    }

    // 20 exact min-extractions fused with v-gather + max
    float vmax = -FLT_MAX;
    #pragma unroll
    for (int it = 0; it < Kk; ++it) {
      unsigned long long m01 = (kc[0] < kc[1]) ? kc[0] : kc[1];
      unsigned long long m23 = (kc[2] < kc[3]) ? kc[2] : kc[3];
      unsigned long long kmin = (m01 < m23) ? m01 : m23;
      #pragma unroll
      for (int d2 = 1; d2 < 64; d2 <<= 1) {
        unsigned long long o =
            (unsigned long long)__shfl_xor((long long)kmin, d2, 64);
        kmin = (o < kmin) ? o : kmin;
      }
      int mI = (int)(kmin & 0xffffffffu) & (Nn - 1);  // masked: can't fault
      vmax = fmaxf(vmax, vb[(size_t)mI * 64 + l]);
      if (kc[0] == kmin) kc[0] = ~0ULL;
      else if (kc[1] == kmin) kc[1] = ~0ULL;
      else if (kc[2] == kmin) kc[2] = ~0ULL;
      else if (kc[3] == kmin) kc[3] = ~0ULL;
    }
    const size_t oidx = (size_t)(gbase + r) * 64 + l;
    out[oidx] = u[oidx] + vmax;
  }
}

extern "C" void kernel_launch(void* const* d_in, const int* in_sizes, int n_in,
                              void* d_out, int out_size, void* d_ws,
                              size_t ws_size, hipStream_t stream) {
  const float* x = (const float*)d_in[0];
  const float* W = (const float*)d_in[1];
  const float* bvec = (const float*)d_in[2];
  // d_in[3] is k (device scalar) — fixed to 20 per problem spec.
  float* u = (float*)d_ws;                                        // 4 MB
  float* v = u + (size_t)Bb * Nn * Ff;                            // 4 MB
  float* sq = v + (size_t)Bb * Nn * Ff;                           // 64 KB
  unsigned short* xhi = (unsigned short*)(sq + (size_t)Bb * Nn);  // 2 MB
  float* out = (float*)d_out;

  uv_kernel2<<<Bb * Nn / RT1, 256, 0, stream>>>(x, W, bvec, u, v, sq, xhi);
  fused_knn_kernel<<<Bb * Nn / NB, 256, 0, stream>>>(x, xhi, sq, u, v, out);
}

// Round 9
// 222.430 us; speedup vs baseline: 1.8557x; 1.8557x over previous
//
#include <hip/hip_runtime.h>
#include <float.h>

// EdgeConv: B=4, N=4096, Fin=64, Fout=64, K=20
// out[b,n,o] = u[b,n,o] + max_{m in knn20(n)} v[b,m,o]
//   u = x.(W1-W2)^T + bias ; v = x.W2^T
// knn on d = sq[n] + sq[m] - 2 x_n.x_m (>=0), self excluded.
//
// R9 = R8 fusion, spill-proofed. R8's 409 MB WRITE_SIZE (vs 4 MB of real
// output) was scratch spill: launch_bounds(256,4) + er-loop selection state.
// Fix: 1024-thread blocks (16 waves); wave w does key phase for m-strip
// [w*256,(w+1)*256) over the block's 16 n-rows, then selects ONE row (row w)
// with tiny register state (2x uint4 + 4 named u64). No launch_bounds cap.
// Quad-min 4:1 keys in 33 KB LDS; keys never leave the CU.

constexpr int Bb = 4, Nn = 4096, Ff = 64, Kk = 20;
constexpr int NB = 16;         // n-rows per fused block
constexpr int QSTRIDE = 1032;  // u16 per LDS quad row (1024 + 8 pad)
constexpr int CCAP = 64;       // candidate quads per row

typedef __attribute__((ext_vector_type(8))) short bf16x8;
typedef __attribute__((ext_vector_type(4))) float f32x4;

__device__ inline unsigned int bf16rn(float f) {
  unsigned int u = __float_as_uint(f);
  return (u + 0x7fffu + ((u >> 16) & 1u)) >> 16;
}

// ---------------- K1: u, v, sq, xhi (16-row fragment swizzle) ----------------
constexpr int RT1 = 16;  // rows per block

__global__ __launch_bounds__(256) void uv_kernel2(
    const float* __restrict__ x, const float* __restrict__ W,
    const float* __restrict__ bvec, float* __restrict__ u,
    float* __restrict__ v, float* __restrict__ sq,
    unsigned short* __restrict__ xhi) {
  __shared__ __align__(16) float4 Ws[64 * 33];   // W row o at granules [33o,33o+32)
  __shared__ __align__(16) float4 xs[RT1 * 16];  // x row r at [16r..)
  const int t = threadIdx.x, l = t & 63, w = t >> 6;
  const int bn0 = blockIdx.x * RT1;
  #pragma unroll
  for (int i = 0; i < 8; i++) {
    int f = t + 256 * i;  // f4 index into W (64 rows x 32 f4)
    Ws[(f >> 5) * 33 + (f & 31)] = ((const float4*)W)[f];
  }
  xs[t] = ((const float4*)x)[bn0 * 16 + t];
  __syncthreads();
  // bf16 split -> 16-row MFMA-fragment swizzle:
  // flat = (ng>>4)*1024 + (k>>5)*512 + ((k>>3)&3)*128 + (ng&15)*8 + (k&7)
  #pragma unroll
  for (int i = 0; i < 4; i++) {
    int idx = t + 256 * i;   // 0..1023 within block's 16 rows
    int nloc = idx >> 6;     // row within block
    int k = idx & 63;        // channel
    float val = ((const float*)xs)[idx];
    unsigned int hb = bf16rn(val);
    int ng = bn0 + nloc;  // global flat row
    size_t flat = ((size_t)(ng >> 4) << 10) + ((size_t)(k >> 5) << 9) +
                  ((size_t)((k >> 3) & 3) << 7) + ((size_t)(ng & 15) << 3) +
                  (size_t)(k & 7);
    xhi[flat] = (unsigned short)hb;
  }
  // sq for rows 4w..4w+3
  #pragma unroll
  for (int i = 0; i < 4; i++) {
    int r = 4 * w + i;
    float val = ((const float*)&xs[r * 16])[l];
    float s = val * val;
    #pragma unroll
    for (int d = 32; d; d >>= 1) s += __shfl_xor(s, d, 64);
    if (l == 0) sq[bn0 + r] = s;
  }
  const int o = l;
  float ua[4] = {0.f, 0.f, 0.f, 0.f}, va[4] = {0.f, 0.f, 0.f, 0.f};
  #pragma unroll
  for (int c = 0; c < 16; c++) {
    float4 w1 = Ws[o * 33 + c];
    float4 w2 = Ws[o * 33 + 16 + c];
    float4 wd;
    wd.x = w1.x - w2.x; wd.y = w1.y - w2.y;
    wd.z = w1.z - w2.z; wd.w = w1.w - w2.w;
    #pragma unroll
    for (int i = 0; i < 4; i++) {
      float4 xv = xs[(4 * w + i) * 16 + c];
      ua[i] += xv.x * wd.x + xv.y * wd.y + xv.z * wd.z + xv.w * wd.w;
      va[i] += xv.x * w2.x + xv.y * w2.y + xv.z * w2.z + xv.w * w2.w;
    }
  }
  float bo = bvec[o];
  #pragma unroll
  for (int i = 0; i < 4; i++) {
    size_t row = (size_t)(bn0 + 4 * w + i);
    u[row * 64 + o] = ua[i] + bo;
    v[row * 64 + o] = va[i];
  }
}

// ---------------- Fused knn: keys + quad-min + select + output ------------
// Grid 1024 blocks (4 batches x 256 n-tiles of 16 rows). Block = 16 waves.
// Key phase: wave w covers m in [w*256,(w+1)*256) = 16 tiles of 16x16x32
// MFMA (hi-bf16, 1 product); quad = 4 consecutive tiles within a 64-m group.
// Quad q (0..1023): members m = (q>>6)*256 + ((q>>4)&3)*64 + (q&15) + 16*i.
// A/B frag (16x16x32): lane = idx(l&15) + 16*koctet(l>>4), 8 contiguous k.
// C/D: col=lane&15, row=(lane>>4)*4+reg [m89/m91].
// Select phase: wave w owns row w exclusively (no er-loop, no cross-wave).

__global__ __launch_bounds__(1024) void fused_knn_kernel(
    const float* __restrict__ x, const unsigned short* __restrict__ xhi,
    const float* __restrict__ sq, const float* __restrict__ u,
    const float* __restrict__ v, float* __restrict__ out) {
  __shared__ __align__(16) unsigned short qminS[NB * QSTRIDE];  // 33 KB
  __shared__ int candS[NB * CCAP];                              // 4 KB
  __shared__ int ccntS[NB];

  const int t = threadIdx.x, l = t & 63, w = t >> 6;  // w in 0..15
  const int blk = blockIdx.x;
  const int b = blk >> 8;
  const int n0 = (blk & 255) * NB;  // batch-local base row
  const int gbase = b * Nn + n0;    // global flat base row
  const int c16 = l & 15;           // col / row-idx lane field
  const int q16 = l >> 4;           // k-octet / row-group lane field

  if (l == 0) ccntS[w] = 0;  // wave-private counter; ordered by barrier

  // A fragments: rows gbase..gbase+15, k-halves 0/1
  const size_t Abase = (size_t)(gbase >> 4) << 10;
  const bf16x8 A0 = *(const bf16x8*)(xhi + Abase + ((size_t)l << 3));
  const bf16x8 A1 = *(const bf16x8*)(xhi + Abase + 512 + ((size_t)l << 3));

  float sqn[4];
  #pragma unroll
  for (int e = 0; e < 4; e++) sqn[e] = sq[gbase + q16 * 4 + e];
  const float* sqb = sq + b * Nn;

  // ---- key phase: 4 groups x 4 tiles ----
  for (int g = 0; g < 4; ++g) {
    unsigned int qmin[4];
    #pragma unroll
    for (int j = 0; j < 4; ++j) {
      const int m0 = w * 256 + g * 64 + j * 16;
      const size_t Bbase = (size_t)((b * Nn + m0) >> 4) << 10;
      bf16x8 B0 = *(const bf16x8*)(xhi + Bbase + ((size_t)l << 3));
      bf16x8 B1 = *(const bf16x8*)(xhi + Bbase + 512 + ((size_t)l << 3));
      f32x4 acc = {0.f, 0.f, 0.f, 0.f};
      acc = __builtin_amdgcn_mfma_f32_16x16x32_bf16(A0, B0, acc, 0, 0, 0);
      acc = __builtin_amdgcn_mfma_f32_16x16x32_bf16(A1, B1, acc, 0, 0, 0);
      const int m = m0 + c16;
      const float sm = sqb[m];
      #pragma unroll
      for (int e = 0; e < 4; e++) {
        float d = fmaxf(sqn[e] + sm - 2.0f * acc[e], 0.f);
        unsigned int key = __float_as_uint(d) >> 15;  // monotone u16
        if (m == n0 + q16 * 4 + e) key = 0xFFFFu;     // self
        qmin[e] = (j == 0) ? key : min(qmin[e], key);
      }
    }
    const int q = w * 64 + g * 16 + c16;
    #pragma unroll
    for (int e = 0; e < 4; e++)
      qminS[(q16 * 4 + e) * QSTRIDE + q] = (unsigned short)qmin[e];
  }
  __syncthreads();

  // ---- selection: wave w owns row w; lane covers quads [l*16, l*16+16) ----
  const uint4* qrow = (const uint4*)(qminS + w * QSTRIDE);
  const uint4 k0 = qrow[2 * l], k1 = qrow[2 * l + 1];
  unsigned int a0 = k0.x, a1 = k0.y, a2 = k0.z, a3 = k0.w;
  unsigned int a4 = k1.x, a5 = k1.y, a6 = k1.z, a7 = k1.w;

  auto countLE = [&](int mid) -> int {
    int c = ((int)(a0 & 0xffffu) <= mid) + ((int)(a0 >> 16) <= mid) +
            ((int)(a1 & 0xffffu) <= mid) + ((int)(a1 >> 16) <= mid) +
            ((int)(a2 & 0xffffu) <= mid) + ((int)(a2 >> 16) <= mid) +
            ((int)(a3 & 0xffffu) <= mid) + ((int)(a3 >> 16) <= mid) +
            ((int)(a4 & 0xffffu) <= mid) + ((int)(a4 >> 16) <= mid) +
            ((int)(a5 & 0xffffu) <= mid) + ((int)(a5 >> 16) <= mid) +
            ((int)(a6 & 0xffffu) <= mid) + ((int)(a6 >> 16) <= mid) +
            ((int)(a7 & 0xffffu) <= mid) + ((int)(a7 >> 16) <= mid);
    #pragma unroll
    for (int d2 = 1; d2 < 64; d2 <<= 1) c += __shfl_xor(c, d2, 64);
    return c;
  };

  unsigned int mn = min(min(min(a0 & 0xffffu, a0 >> 16), min(a1 & 0xffffu, a1 >> 16)),
                        min(min(a2 & 0xffffu, a2 >> 16), min(a3 & 0xffffu, a3 >> 16)));
  mn = min(mn, min(min(min(a4 & 0xffffu, a4 >> 16), min(a5 & 0xffffu, a5 >> 16)),
                   min(min(a6 & 0xffffu, a6 >> 16), min(a7 & 0xffffu, a7 >> 16))));
  #pragma unroll
  for (int d2 = 1; d2 < 64; d2 <<= 1)
    mn = min(mn, (unsigned int)__shfl_xor((int)mn, d2, 64));

  // bounded gallop + bisect on quad counts
  int lo = (int)mn - 1;
  int hi = (int)mn + 64;
  if (hi > 65530) hi = 65530;
  int c = countLE(hi);
  int step = 128;
  while (c < Kk && hi < 65530) {
    lo = hi;
    hi += step;
    if (hi > 65530) hi = 65530;
    step <<= 1;
    c = countLE(hi);
  }
  while (c > 44 && hi - lo > 1) {
    int mid = (lo + hi) >> 1;
    int cm = countLE(mid);
    if (cm >= Kk) { hi = mid; c = cm; } else { lo = mid; }
  }
  const int hc = hi + 4;  // margin: hi-only bf16 keys + quantization

  // collect qualifying quads (wave-private row counter)
  {
    unsigned int as[8] = {a0, a1, a2, a3, a4, a5, a6, a7};
    #pragma unroll
    for (int i = 0; i < 8; i++) {
      int qb = l * 16 + i * 2;
      if ((int)(as[i] & 0xffffu) <= hc) {
        int slot = atomicAdd(&ccntS[w], 1);
        if (slot < CCAP) candS[w * CCAP + slot] = qb;
      }
      if ((int)(as[i] >> 16) <= hc) {
        int slot = atomicAdd(&ccntS[w], 1);
        if (slot < CCAP) candS[w * CCAP + slot] = qb + 1;
      }
    }
  }
  int C = ccntS[w];
  if (C > CCAP) C = CCAP;

  // exact fp32 distances for the 4 members of this lane's candidate quad
  const float4* xb4 = (const float4*)(x + (size_t)b * Nn * Ff);
  const float* vb = v + (size_t)b * Nn * Ff;
  unsigned long long kc0 = ~0ULL, kc1 = ~0ULL, kc2 = ~0ULL, kc3 = ~0ULL;
  if (l < C) {
    int q = candS[w * CCAP + l];
    int mb = ((q >> 6) << 8) + (((q >> 4) & 3) << 6) + (q & 15);
    unsigned long long kk[4];
    #pragma unroll
    for (int i = 0; i < 4; i++) {
      int mI = mb + 16 * i;
      const float4* xmf = xb4 + (size_t)mI * 16;
      float ds = 0.f;
      #pragma unroll
      for (int cc = 0; cc < 16; cc++) {
        float4 an = xb4[(size_t)(n0 + w) * 16 + cc];  // wave-uniform
        float4 bm = xmf[cc];
        float dx = an.x - bm.x, dy = an.y - bm.y, dz = an.z - bm.z,
              dw2 = an.w - bm.w;
        ds += dx * dx + dy * dy + dz * dz + dw2 * dw2;
      }
      if (mI == n0 + w) ds = FLT_MAX;  // self
      kk[i] = ((unsigned long long)__float_as_uint(ds) << 32) | (unsigned int)mI;
    }
    kc0 = kk[0]; kc1 = kk[1]; kc2 = kk[2]; kc3 = kk[3];
  }

  // 20 exact min-extractions fused with v-gather + max
  float vmax = -FLT_MAX;
  #pragma unroll
  for (int it = 0; it < Kk; ++it) {
    unsigned long long m01 = (kc0 < kc1) ? kc0 : kc1;
    unsigned long long m23 = (kc2 < kc3) ? kc2 : kc3;
    unsigned long long kmin = (m01 < m23) ? m01 : m23;
    #pragma unroll
    for (int d2 = 1; d2 < 64; d2 <<= 1) {
      unsigned long long o =
          (unsigned long long)__shfl_xor((long long)kmin, d2, 64);
      kmin = (o < kmin) ? o : kmin;
    }
    int mI = (int)(kmin & 0xffffffffu) & (Nn - 1);  // masked: can't fault
    vmax = fmaxf(vmax, vb[(size_t)mI * 64 + l]);
    if (kc0 == kmin) kc0 = ~0ULL;
    else if (kc1 == kmin) kc1 = ~0ULL;
    else if (kc2 == kmin) kc2 = ~0ULL;
    else if (kc3 == kmin) kc3 = ~0ULL;
  }
  const size_t oidx = (size_t)(gbase + w) * 64 + l;
  out[oidx] = u[oidx] + vmax;
}

extern "C" void kernel_launch(void* const* d_in, const int* in_sizes, int n_in,
                              void* d_out, int out_size, void* d_ws,
                              size_t ws_size, hipStream_t stream) {
  const float* x = (const float*)d_in[0];
  const float* W = (const float*)d_in[1];
  const float* bvec = (const float*)d_in[2];
  // d_in[3] is k (device scalar) — fixed to 20 per problem spec.
  float* u = (float*)d_ws;                                        // 4 MB
  float* v = u + (size_t)Bb * Nn * Ff;                            // 4 MB
  float* sq = v + (size_t)Bb * Nn * Ff;                           // 64 KB
  unsigned short* xhi = (unsigned short*)(sq + (size_t)Bb * Nn);  // 2 MB
  float* out = (float*)d_out;

  uv_kernel2<<<Bb * Nn / RT1, 256, 0, stream>>>(x, W, bvec, u, v, sq, xhi);
  fused_knn_kernel<<<Bb * Nn / NB, 1024, 0, stream>>>(x, xhi, sq, u, v, out);
}

// Round 10
// 186.805 us; speedup vs baseline: 2.2096x; 1.1907x over previous
//
#include <hip/hip_runtime.h>
#include <float.h>

// EdgeConv: B=4, N=4096, Fin=64, Fout=64, K=20
// out[b,n,o] = u[b,n,o] + max_{m in knn20(n)} v[b,m,o]
//   u = x.(W1-W2)^T + bias ; v = x.W2^T
// knn on d = sq[n] + sq[m] - 2 x_n.x_m (>=0), self excluded.
//
// R10 = R9's fused traffic win, convoy broken: K2 does MFMA keys + quad-min
// LDS + bisect + candidate COLLECT only (writes <=64 quad-ids + count per row,
// 2 MB). K3 (one wave/row, no barriers, full occupancy) does exact fp32
// recompute of candidate members + u32-key 20-extraction (ballot/ctz index
// broadcast) + v-gather + output. Bisect stop tightened 44->28.

constexpr int Bb = 4, Nn = 4096, Ff = 64, Kk = 20;
constexpr int NB = 16;         // n-rows per K2 block
constexpr int QSTRIDE = 1032;  // u16 per LDS quad row (1024 + 8 pad)
constexpr int CCAP = 64;       // candidate quads per row

typedef __attribute__((ext_vector_type(8))) short bf16x8;
typedef __attribute__((ext_vector_type(4))) float f32x4;

__device__ inline unsigned int bf16rn(float f) {
  unsigned int u = __float_as_uint(f);
  return (u + 0x7fffu + ((u >> 16) & 1u)) >> 16;
}

// ---------------- K1: u, v, sq, xhi (16-row fragment swizzle) ----------------
constexpr int RT1 = 16;  // rows per block

__global__ __launch_bounds__(256) void uv_kernel2(
    const float* __restrict__ x, const float* __restrict__ W,
    const float* __restrict__ bvec, float* __restrict__ u,
    float* __restrict__ v, float* __restrict__ sq,
    unsigned short* __restrict__ xhi) {
  __shared__ __align__(16) float4 Ws[64 * 33];   // W row o at granules [33o,33o+32)
  __shared__ __align__(16) float4 xs[RT1 * 16];  // x row r at [16r..)
  const int t = threadIdx.x, l = t & 63, w = t >> 6;
  const int bn0 = blockIdx.x * RT1;
  #pragma unroll
  for (int i = 0; i < 8; i++) {
    int f = t + 256 * i;  // f4 index into W (64 rows x 32 f4)
    Ws[(f >> 5) * 33 + (f & 31)] = ((const float4*)W)[f];
  }
  xs[t] = ((const float4*)x)[bn0 * 16 + t];
  __syncthreads();
  // bf16 split -> 16-row MFMA-fragment swizzle:
  // flat = (ng>>4)*1024 + (k>>5)*512 + ((k>>3)&3)*128 + (ng&15)*8 + (k&7)
  #pragma unroll
  for (int i = 0; i < 4; i++) {
    int idx = t + 256 * i;   // 0..1023 within block's 16 rows
    int nloc = idx >> 6;     // row within block
    int k = idx & 63;        // channel
    float val = ((const float*)xs)[idx];
    unsigned int hb = bf16rn(val);
    int ng = bn0 + nloc;  // global flat row
    size_t flat = ((size_t)(ng >> 4) << 10) + ((size_t)(k >> 5) << 9) +
                  ((size_t)((k >> 3) & 3) << 7) + ((size_t)(ng & 15) << 3) +
                  (size_t)(k & 7);
    xhi[flat] = (unsigned short)hb;
  }
  // sq for rows 4w..4w+3
  #pragma unroll
  for (int i = 0; i < 4; i++) {
    int r = 4 * w + i;
    float val = ((const float*)&xs[r * 16])[l];
    float s = val * val;
    #pragma unroll
    for (int d = 32; d; d >>= 1) s += __shfl_xor(s, d, 64);
    if (l == 0) sq[bn0 + r] = s;
  }
  const int o = l;
  float ua[4] = {0.f, 0.f, 0.f, 0.f}, va[4] = {0.f, 0.f, 0.f, 0.f};
  #pragma unroll
  for (int c = 0; c < 16; c++) {
    float4 w1 = Ws[o * 33 + c];
    float4 w2 = Ws[o * 33 + 16 + c];
    float4 wd;
    wd.x = w1.x - w2.x; wd.y = w1.y - w2.y;
    wd.z = w1.z - w2.z; wd.w = w1.w - w2.w;
    #pragma unroll
    for (int i = 0; i < 4; i++) {
      float4 xv = xs[(4 * w + i) * 16 + c];
      ua[i] += xv.x * wd.x + xv.y * wd.y + xv.z * wd.z + xv.w * wd.w;
      va[i] += xv.x * w2.x + xv.y * w2.y + xv.z * w2.z + xv.w * w2.w;
    }
  }
  float bo = bvec[o];
  #pragma unroll
  for (int i = 0; i < 4; i++) {
    size_t row = (size_t)(bn0 + 4 * w + i);
    u[row * 64 + o] = ua[i] + bo;
    v[row * 64 + o] = va[i];
  }
}

// ---------------- K2: keys + quad-min + bisect + candidate collect --------
// Grid 1024 blocks (4 batches x 256 n-tiles of 16 rows). Block = 16 waves.
// Key phase: wave w covers m in [w*256,(w+1)*256); quad q (0..1023):
// members m = (q>>6)*256 + ((q>>4)&3)*64 + (q&15) + 16*i, i=0..3.
// A/B frag (16x16x32): lane = idx(l&15) + 16*koctet(l>>4), 8 contiguous k.
// C/D: col=lane&15, row=(lane>>4)*4+reg [m89/m91].
// Select-lite: wave w bisects row w, writes <=CCAP quad ids + count to global.

__global__ __launch_bounds__(1024) void key_select_kernel(
    const unsigned short* __restrict__ xhi, const float* __restrict__ sq,
    unsigned short* __restrict__ candG, int* __restrict__ cntG) {
  __shared__ __align__(16) unsigned short qminS[NB * QSTRIDE];  // 33 KB
  __shared__ int candS[NB * CCAP];                              // 4 KB
  __shared__ int ccntS[NB];

  const int t = threadIdx.x, l = t & 63, w = t >> 6;  // w in 0..15
  const int blk = blockIdx.x;
  const int b = blk >> 8;
  const int n0 = (blk & 255) * NB;  // batch-local base row
  const int gbase = b * Nn + n0;    // global flat base row
  const int c16 = l & 15;
  const int q16 = l >> 4;

  if (l == 0) ccntS[w] = 0;  // wave-private counter (in-wave LDS order)

  const size_t Abase = (size_t)(gbase >> 4) << 10;
  const bf16x8 A0 = *(const bf16x8*)(xhi + Abase + ((size_t)l << 3));
  const bf16x8 A1 = *(const bf16x8*)(xhi + Abase + 512 + ((size_t)l << 3));

  float sqn[4];
  #pragma unroll
  for (int e = 0; e < 4; e++) sqn[e] = sq[gbase + q16 * 4 + e];
  const float* sqb = sq + b * Nn;

  // ---- key phase: 4 groups x 4 tiles ----
  for (int g = 0; g < 4; ++g) {
    unsigned int qmin[4];
    #pragma unroll
    for (int j = 0; j < 4; ++j) {
      const int m0 = w * 256 + g * 64 + j * 16;
      const size_t Bbase = (size_t)((b * Nn + m0) >> 4) << 10;
      bf16x8 B0 = *(const bf16x8*)(xhi + Bbase + ((size_t)l << 3));
      bf16x8 B1 = *(const bf16x8*)(xhi + Bbase + 512 + ((size_t)l << 3));
      f32x4 acc = {0.f, 0.f, 0.f, 0.f};
      acc = __builtin_amdgcn_mfma_f32_16x16x32_bf16(A0, B0, acc, 0, 0, 0);
      acc = __builtin_amdgcn_mfma_f32_16x16x32_bf16(A1, B1, acc, 0, 0, 0);
      const int m = m0 + c16;
      const float sm = sqb[m];
      #pragma unroll
      for (int e = 0; e < 4; e++) {
        float d = fmaxf(sqn[e] + sm - 2.0f * acc[e], 0.f);
        unsigned int key = __float_as_uint(d) >> 15;  // monotone u16
        if (m == n0 + q16 * 4 + e) key = 0xFFFFu;     // self
        qmin[e] = (j == 0) ? key : min(qmin[e], key);
      }
    }
    const int q = w * 64 + g * 16 + c16;
    #pragma unroll
    for (int e = 0; e < 4; e++)
      qminS[(q16 * 4 + e) * QSTRIDE + q] = (unsigned short)qmin[e];
  }
  __syncthreads();

  // ---- select-lite: wave w owns row w; lane covers quads [l*16, l*16+16) ----
  const uint4* qrow = (const uint4*)(qminS + w * QSTRIDE);
  const uint4 k0 = qrow[2 * l], k1 = qrow[2 * l + 1];
  unsigned int a0 = k0.x, a1 = k0.y, a2 = k0.z, a3 = k0.w;
  unsigned int a4 = k1.x, a5 = k1.y, a6 = k1.z, a7 = k1.w;

  auto countLE = [&](int mid) -> int {
    int c = ((int)(a0 & 0xffffu) <= mid) + ((int)(a0 >> 16) <= mid) +
            ((int)(a1 & 0xffffu) <= mid) + ((int)(a1 >> 16) <= mid) +
            ((int)(a2 & 0xffffu) <= mid) + ((int)(a2 >> 16) <= mid) +
            ((int)(a3 & 0xffffu) <= mid) + ((int)(a3 >> 16) <= mid) +
            ((int)(a4 & 0xffffu) <= mid) + ((int)(a4 >> 16) <= mid) +
            ((int)(a5 & 0xffffu) <= mid) + ((int)(a5 >> 16) <= mid) +
            ((int)(a6 & 0xffffu) <= mid) + ((int)(a6 >> 16) <= mid) +
            ((int)(a7 & 0xffffu) <= mid) + ((int)(a7 >> 16) <= mid);
    #pragma unroll
    for (int d2 = 1; d2 < 64; d2 <<= 1) c += __shfl_xor(c, d2, 64);
    return c;
  };

  unsigned int mn = min(min(min(a0 & 0xffffu, a0 >> 16), min(a1 & 0xffffu, a1 >> 16)),
                        min(min(a2 & 0xffffu, a2 >> 16), min(a3 & 0xffffu, a3 >> 16)));
  mn = min(mn, min(min(min(a4 & 0xffffu, a4 >> 16), min(a5 & 0xffffu, a5 >> 16)),
                   min(min(a6 & 0xffffu, a6 >> 16), min(a7 & 0xffffu, a7 >> 16))));
  #pragma unroll
  for (int d2 = 1; d2 < 64; d2 <<= 1)
    mn = min(mn, (unsigned int)__shfl_xor((int)mn, d2, 64));

  // bounded gallop + bisect on quad counts (stop at c<=28)
  int lo = (int)mn - 1;
  int hi = (int)mn + 64;
  if (hi > 65530) hi = 65530;
  int c = countLE(hi);
  int step = 128;
  while (c < Kk && hi < 65530) {
    lo = hi;
    hi += step;
    if (hi > 65530) hi = 65530;
    step <<= 1;
    c = countLE(hi);
  }
  while (c > 28 && hi - lo > 1) {
    int mid = (lo + hi) >> 1;
    int cm = countLE(mid);
    if (cm >= Kk) { hi = mid; c = cm; } else { lo = mid; }
  }
  const int hc = hi + 4;  // margin: hi-only bf16 keys + quantization

  // collect qualifying quads (wave-private row counter)
  {
    unsigned int as[8] = {a0, a1, a2, a3, a4, a5, a6, a7};
    #pragma unroll
    for (int i = 0; i < 8; i++) {
      int qb = l * 16 + i * 2;
      if ((int)(as[i] & 0xffffu) <= hc) {
        int slot = atomicAdd(&ccntS[w], 1);
        if (slot < CCAP) candS[w * CCAP + slot] = qb;
      }
      if ((int)(as[i] >> 16) <= hc) {
        int slot = atomicAdd(&ccntS[w], 1);
        if (slot < CCAP) candS[w * CCAP + slot] = qb + 1;
      }
    }
  }
  int C = ccntS[w];
  if (C > CCAP) C = CCAP;
  if (l == 0) cntG[gbase + w] = C;
  if (l < C) candG[(size_t)(gbase + w) * CCAP + l] =
      (unsigned short)candS[w * CCAP + l];
}

// ---------------- K3: exact recompute + top-20 + v-gather + output --------
// One wave per row; 4 rows per 256-thread block; no barriers.

__global__ __launch_bounds__(256) void topk_kernel(
    const float* __restrict__ x, const unsigned short* __restrict__ candG,
    const int* __restrict__ cntG, const float* __restrict__ u,
    const float* __restrict__ v, float* __restrict__ out) {
  const int t = threadIdx.x, l = t & 63, w = t >> 6;
  const int row = blockIdx.x * 4 + w;  // flat b*N+n
  const int rowu = __builtin_amdgcn_readfirstlane(row);
  const int b = rowu >> 12, n = rowu & (Nn - 1);
  const int C = min(cntG[rowu], CCAP);

  const float4* xb4 = (const float4*)(x + (size_t)b * Nn * Ff);
  const float* vb = v + (size_t)b * Nn * Ff;

  unsigned int kk0 = ~0u, kk1 = ~0u, kk2 = ~0u, kk3 = ~0u;
  int mi0 = 0, mi1 = 0, mi2 = 0, mi3 = 0;
  if (l < C) {
    int q = candG[(size_t)rowu * CCAP + l];
    int mb = ((q >> 6) << 8) + (((q >> 4) & 3) << 6) + (q & 15);
    unsigned int kk[4];
    int mm[4];
    #pragma unroll
    for (int i = 0; i < 4; i++) {
      int mI = mb + 16 * i;
      const float4* xmf = xb4 + (size_t)mI * 16;
      float ds = 0.f;
      #pragma unroll
      for (int cc = 0; cc < 16; cc++) {
        float4 an = xb4[(size_t)n * 16 + cc];  // wave-uniform
        float4 bm = xmf[cc];
        float dx = an.x - bm.x, dy = an.y - bm.y, dz = an.z - bm.z,
              dw2 = an.w - bm.w;
        ds += dx * dx + dy * dy + dz * dz + dw2 * dw2;
      }
      if (mI == n) ds = FLT_MAX;  // self
      kk[i] = __float_as_uint(ds);  // monotone u32 for ds>=0
      mm[i] = mI;
    }
    kk0 = kk[0]; kk1 = kk[1]; kk2 = kk[2]; kk3 = kk[3];
    mi0 = mm[0]; mi1 = mm[1]; mi2 = mm[2]; mi3 = mm[3];
  }

  // 20 min-extractions on u32 keys; index via ballot/ctz + shfl broadcast
  float vmax = -FLT_MAX;
  #pragma unroll
  for (int it = 0; it < Kk; ++it) {
    unsigned int lmin = min(min(kk0, kk1), min(kk2, kk3));
    unsigned int wmin = lmin;
    #pragma unroll
    for (int d2 = 1; d2 < 64; d2 <<= 1)
      wmin = min(wmin, (unsigned int)__shfl_xor((int)wmin, d2, 64));
    int myIdx = (kk0 == lmin) ? mi0
              : (kk1 == lmin) ? mi1
              : (kk2 == lmin) ? mi2 : mi3;
    unsigned long long mask = __ballot(lmin == wmin);
    int src = __builtin_ctzll(mask);
    int mI = __shfl(myIdx, src, 64) & (Nn - 1);  // masked: can't fault
    vmax = fmaxf(vmax, vb[(size_t)mI * 64 + l]);
    if (l == src) {
      if (kk0 == wmin) kk0 = ~0u;
      else if (kk1 == wmin) kk1 = ~0u;
      else if (kk2 == wmin) kk2 = ~0u;
      else kk3 = ~0u;
    }
  }
  const size_t oidx = (size_t)rowu * 64 + l;
  out[oidx] = u[oidx] + vmax;
}

extern "C" void kernel_launch(void* const* d_in, const int* in_sizes, int n_in,
                              void* d_out, int out_size, void* d_ws,
                              size_t ws_size, hipStream_t stream) {
  const float* x = (const float*)d_in[0];
  const float* W = (const float*)d_in[1];
  const float* bvec = (const float*)d_in[2];
  // d_in[3] is k (device scalar) — fixed to 20 per problem spec.
  float* u = (float*)d_ws;                                        // 4 MB
  float* v = u + (size_t)Bb * Nn * Ff;                            // 4 MB
  float* sq = v + (size_t)Bb * Nn * Ff;                           // 64 KB
  unsigned short* xhi = (unsigned short*)(sq + (size_t)Bb * Nn);  // 2 MB
  unsigned short* candG = xhi + (size_t)Bb * Nn * Ff;             // 2 MB
  int* cntG = (int*)(candG + (size_t)Bb * Nn * CCAP);             // 64 KB
  float* out = (float*)d_out;

  uv_kernel2<<<Bb * Nn / RT1, 256, 0, stream>>>(x, W, bvec, u, v, sq, xhi);
  key_select_kernel<<<Bb * Nn / NB, 1024, 0, stream>>>(xhi, sq, candG, cntG);
  topk_kernel<<<Bb * Nn / 4, 256, 0, stream>>>(x, candG, cntG, u, v, out);
}